// Round 9
// baseline (452.873 us; speedup 1.0000x reference)
//
#include <hip/hip_runtime.h>
#include <hip/hip_bf16.h>
#include <cmath>
#include <cstdint>

typedef short s16x8 __attribute__((ext_vector_type(8)));
typedef float f32x4 __attribute__((ext_vector_type(4)));

__device__ __forceinline__ float bf2f(uint16_t u) {
  union { uint32_t i; float f; } c; c.i = ((uint32_t)u) << 16; return c.f;
}
__device__ __forceinline__ uint16_t f2bf(float f) {
  union { float f; uint32_t i; } c; c.f = f;
  return (uint16_t)((c.i + 0x7FFFu + ((c.i >> 16) & 1u)) >> 16);
}
// packed f32x2 -> bf16x2 (RNE), low word = a
__device__ __forceinline__ uint32_t pkbf(float a, float b) {
  union { __hip_bfloat162 h; uint32_t u; } c;
  c.h = __float22bfloat162_rn(float2{a, b});
  return c.u;
}

// async global->LDS, 16B/lane; lane i lands at (uniform base) + 16*i
__device__ __forceinline__ void gload16(const void* g, void* l) {
  __builtin_amdgcn_global_load_lds(
      (const __attribute__((address_space(1))) void*)g,
      (__attribute__((address_space(3))) void*)l, 16, 0, 0);
}

// ---- dtype sniff: bf16 data -> even 16-bit words have sane exponents ----
__device__ __forceinline__ bool sniff_is_bf16(const uint16_t* u16, int64_t n,
                                              int tid, int* s_cnt) {
  int cnt = 0;
#pragma unroll
  for (int j = 0; j < 4; j++) {
    int64_t idx = (((int64_t)(tid * 4 + j)) * 2) % n;
    idx &= ~(int64_t)1;
    uint32_t e = (u16[idx] >> 7) & 0xFF;
    cnt += (e >= 96 && e <= 144) ? 1 : 0;
  }
  if (tid == 0) *s_cnt = 0;
  __syncthreads();
  atomicAdd(s_cnt, cnt);
  __syncthreads();
  return (*s_cnt) * 10 > 1024 * 6;
}

// ------ ONE fused prep dispatch: zero d_out + converts + 6 transposes -----
// blocks [0,4096): zero d_out; [4096,5120): cvt x; [5120,7168): cvt ctx;
// 7168/7169/7170: biases; [7171,19459): weight transposes.
__global__ __launch_bounds__(256) void prep_all(
    float* dout,
    const void* xr, const void* cr, const void* bor, const void* b1r, const void* b2r,
    const void* Wq, const void* Wk, const void* Wv, const void* Wo,
    const void* W1, const void* W2,
    uint16_t* xo, uint16_t* co, uint16_t* boo, uint16_t* b1o, uint16_t* b2o,
    uint16_t* WqT, uint16_t* WkT, uint16_t* WvT, uint16_t* WoT,
    uint16_t* W1T, uint16_t* W2T) {
  __shared__ int s_cnt;
  __shared__ uint16_t tile[32][34];
  const int id = blockIdx.x;
  const int tid = threadIdx.x;

  if (id < 4096) {  // zero d_out (16 MB fp32)
    const int64_t i = ((int64_t)id * 256 + tid) * 4;
    *(f32x4*)(dout + i) = (f32x4){0.f, 0.f, 0.f, 0.f};
    return;
  }
  if (id < 7171) {  // linear converts
    const void* src; uint16_t* dst; int64_t tot; int64_t base; int n;
    if (id < 5120)      { src = xr;  dst = xo;  tot = 4194304; base = (int64_t)(id - 4096) * 4096; n = 4096; }
    else if (id < 7168) { src = cr;  dst = co;  tot = 8388608; base = (int64_t)(id - 5120) * 4096; n = 4096; }
    else if (id == 7168){ src = bor; dst = boo; tot = 1024; base = 0; n = 1024; }
    else if (id == 7169){ src = b1r; dst = b1o; tot = 4096; base = 0; n = 4096; }
    else                { src = b2r; dst = b2o; tot = 1024; base = 0; n = 1024; }
    const bool is16 = sniff_is_bf16((const uint16_t*)src, tot, tid, &s_cnt);
    for (int i = tid; i < n; i += 256) {
      const int64_t gi = base + i;
      dst[gi] = is16 ? ((const uint16_t*)src)[gi] : f2bf(((const float*)src)[gi]);
    }
    return;
  }
  // transposes: in[R][C] -> out[C][R]
  const int t0 = id - 7171;
  const void* src; uint16_t* dst; int R, C, bx, by;
  if (t0 < 1024)      { src = Wq; dst = WqT; R = 1024; C = 1024; bx = t0 & 31; by = t0 >> 5; }
  else if (t0 < 2048) { int t = t0 - 1024; src = Wk; dst = WkT; R = 1024; C = 1024; bx = t & 31; by = t >> 5; }
  else if (t0 < 3072) { int t = t0 - 2048; src = Wv; dst = WvT; R = 1024; C = 1024; bx = t & 31; by = t >> 5; }
  else if (t0 < 4096) { int t = t0 - 3072; src = Wo; dst = WoT; R = 1024; C = 1024; bx = t & 31; by = t >> 5; }
  else if (t0 < 8192) { int t = t0 - 4096; src = W1; dst = W1T; R = 1024; C = 4096; bx = t & 127; by = t >> 7; }
  else                { int t = t0 - 8192; src = W2; dst = W2T; R = 4096; C = 1024; bx = t & 31; by = t >> 5; }
  const uint16_t* u16 = (const uint16_t*)src;
  const float* f32 = (const float*)src;
  const bool is16 = sniff_is_bf16(u16, (int64_t)R * C, tid, &s_cnt);
  const int tx = tid & 31, ty = tid >> 5;
  const int c0 = bx * 32, r0 = by * 32;
#pragma unroll
  for (int i = 0; i < 4; i++) {
    const int r = ty + i * 8;
    const int64_t gi = (int64_t)(r0 + r) * C + c0 + tx;
    tile[r][tx] = is16 ? u16[gi] : f2bf(f32[gi]);
  }
  __syncthreads();
#pragma unroll
  for (int i = 0; i < 4; i++) {
    const int r = ty + i * 8;
    dst[(int64_t)(c0 + r) * R + r0 + tx] = tile[tx][r];
  }
}

// ---- fused per-batch V transpose: KVb[b*2048+k][1024+c] -> Vt[b][c][k] ----
__global__ __launch_bounds__(256) void vtrans(
    const uint16_t* __restrict__ KVb, uint16_t* __restrict__ Vt) {
  __shared__ uint16_t tile[32][34];
  const int z = blockIdx.z;
  const uint16_t* in = KVb + (int64_t)z * 2048 * 2048 + 1024;  // stride 2048
  uint16_t* out = Vt + (int64_t)z * 1024 * 2048;
  const int tx = threadIdx.x & 31, ty = threadIdx.x >> 5;
  const int c0 = blockIdx.x * 32, r0 = blockIdx.y * 32;
#pragma unroll
  for (int i = 0; i < 4; i++) {
    const int r = ty + i * 8;
    tile[r][tx] = in[(int64_t)(r0 + r) * 2048 + c0 + tx];
  }
  __syncthreads();
#pragma unroll
  for (int i = 0; i < 4; i++) {
    const int r = ty + i * 8;
    out[(int64_t)(c0 + r) * 2048 + r0 + tx] = tile[tx][r];
  }
}

// ---------------- GEMM v4: BK=64, global_load_lds, XOR chunk swizzle ------
#define BM 128
#define BN 128
#define BK 64

enum { EPI_NONE = 0, EPI_BIAS_RES = 1, EPI_BIAS_GELU = 2 };

template <int EPI, int RESF32, int OUTF32, int SPLITK>
__device__ __forceinline__ void gemm_body(
    const uint16_t* __restrict__ A, const uint16_t* __restrict__ Bt,
    void* __restrict__ Cv, const uint16_t* __restrict__ bias,
    const void* __restrict__ resid, int M, int N, int K_total,
    int m0, int n0, int zslice, uint16_t* As, uint16_t* Bs) {
  const int tid = threadIdx.x;
  const int w = tid >> 6, l = tid & 63;
  const int wu = __builtin_amdgcn_readfirstlane(w);
  const int wm = (w >> 1) * 64, wn = (w & 1) * 64;
  const int ls = l & 15, lg = l >> 4;
  const int K = SPLITK ? (K_total >> 1) : K_total;
  const int kof = SPLITK ? zslice * K : 0;

  const int sr = 8 * w + (l >> 3);
  const int koff = (((l & 7) ^ ((l >> 3) & 7)) * 8);
  const uint16_t* Ag = A + (int64_t)(m0 + sr) * K_total + kof + koff;
  const uint16_t* Bg = Bt + (int64_t)(n0 + sr) * K_total + kof + koff;
  const int64_t rstep = (int64_t)32 * K_total;

  uint16_t* lA = As + wu * 512;
  uint16_t* lB = Bs + wu * 512;

  f32x4 acc[4][4] = {};

  for (int kb = 0; kb < K; kb += BK) {
    __syncthreads();
#pragma unroll
    for (int r = 0; r < 4; r++) {
      gload16(Ag + r * rstep + kb, lA + r * 2048);
      gload16(Bg + r * rstep + kb, lB + r * 2048);
    }
    __syncthreads();
#pragma unroll
    for (int kk = 0; kk < 2; kk++) {
      s16x8 af[4], bfr[4];
#pragma unroll
      for (int i = 0; i < 4; i++) {
        const int row = wm + i * 16 + ls;
        af[i] = *(const s16x8*)&As[row * 64 + (((kk * 4 + lg) ^ (ls & 7)) * 8)];
      }
#pragma unroll
      for (int j = 0; j < 4; j++) {
        const int row = wn + j * 16 + ls;
        bfr[j] = *(const s16x8*)&Bs[row * 64 + (((kk * 4 + lg) ^ (ls & 7)) * 8)];
      }
#pragma unroll
      for (int i = 0; i < 4; i++)
#pragma unroll
        for (int j = 0; j < 4; j++)
          acc[i][j] = __builtin_amdgcn_mfma_f32_16x16x32_bf16(af[i], bfr[j], acc[i][j], 0, 0, 0);
    }
  }

#pragma unroll
  for (int i = 0; i < 4; i++) {
#pragma unroll
    for (int rr = 0; rr < 4; rr++) {
      const int64_t row = m0 + wm + i * 16 + lg * 4 + rr;
#pragma unroll
      for (int j = 0; j < 4; j++) {
        const int col = n0 + wn + j * 16 + ls;
        float v = acc[i][j][rr];
        if (EPI == EPI_BIAS_RES) {
          if (!SPLITK || zslice == 0) {
            const float rv = RESF32 ? ((const float*)resid)[row * N + col]
                                    : bf2f(((const uint16_t*)resid)[row * N + col]);
            v += bf2f(bias[col]) + rv;
          }
        } else if (EPI == EPI_BIAS_GELU) {
          v += bf2f(bias[col]);
          v = 0.5f * v * (1.0f + erff(v * 0.70710678118654752f));  // exact GELU
        }
        if (SPLITK)
          atomicAdd((float*)Cv + row * N + col, v);
        else if (OUTF32)
          ((float*)Cv)[row * N + col] = v;
        else
          ((uint16_t*)Cv)[row * N + col] = f2bf(v);
      }
    }
  }
}

template <int EPI, int RESF32, int OUTF32, int SPLITK>
__global__ __launch_bounds__(256, 3) void gemm_single(
    const uint16_t* __restrict__ A, const uint16_t* __restrict__ Bt,
    void* __restrict__ Cv, const uint16_t* __restrict__ bias,
    const void* __restrict__ resid, int M, int N, int K_total) {
  __shared__ alignas(16) uint16_t As[BM * BK];
  __shared__ alignas(16) uint16_t Bs[BN * BK];
  gemm_body<EPI, RESF32, OUTF32, SPLITK>(A, Bt, Cv, bias, resid, M, N, K_total,
                                         blockIdx.x * BM, blockIdx.y * BN,
                                         (int)blockIdx.z, As, Bs);
}

// grouped Q-proj + KV-proj: blocks [0,256) Q, [256,1280) KV. K=1024 both.
__global__ __launch_bounds__(256, 3) void gemm_qkv(
    const uint16_t* __restrict__ xA, const uint16_t* __restrict__ WqT,
    uint16_t* __restrict__ Qb,
    const uint16_t* __restrict__ ctxA, const uint16_t* __restrict__ KVWt,
    uint16_t* __restrict__ KVb) {
  __shared__ alignas(16) uint16_t As[BM * BK];
  __shared__ alignas(16) uint16_t Bs[BN * BK];
  const int id = blockIdx.x;
  if (id < 256) {
    gemm_body<EPI_NONE, 0, 0, 0>(xA, WqT, Qb, nullptr, nullptr, 4096, 1024, 1024,
                                 (id & 31) * BM, (id >> 5) * BN, 0, As, Bs);
  } else {
    const int t = id - 256;
    gemm_body<EPI_NONE, 0, 0, 0>(ctxA, KVWt, KVb, nullptr, nullptr, 8192, 2048, 1024,
                                 (t & 63) * BM, (t >> 6) * BN, 0, As, Bs);
  }
}

// ---------------- flash cross-attention v5 --------------------------------
// 256 threads, 4 waves x 32 q-rows (2 subtiles of 16) = 128 q-rows per block;
// grid 512, XCD swizzle (bh = blk&63). S computed TRANSPOSED (A=K, B=Q) so P
// packs to b64 LDS writes and row-sums are lane-local. K/V frag reads SHARED
// across both q-subtiles (the R8 LDS-throughput fix: 144 -> 80 b128/blk-iter).
#define KLD 72
#define PLD 72

__global__ __launch_bounds__(256, 2) void attn_kernel(
    const uint16_t* __restrict__ Q,   // [B*1024][1024]
    const uint16_t* __restrict__ KV,  // [B*2048][2048]; cols 0..1023 = K
    const uint16_t* __restrict__ Vt,  // [B][1024 (h*64+d)][2048 (key)]
    uint16_t* __restrict__ O) {       // [B*1024][1024]
  __shared__ alignas(16) uint16_t Ks[64 * KLD];
  __shared__ alignas(16) uint16_t Vts[64 * KLD];
  __shared__ alignas(16) uint16_t Ps[8][16 * PLD];  // [w*2+qq]

  const int tid = threadIdx.x;
  const int w = tid >> 6, l = tid & 63;
  const int ls = l & 15, lg = l >> 4;

  const int blk = blockIdx.x;
  const int bh = blk & 63;   // XCD = bh%8 for all 8 q-blocks of this (b,h)
  const int qb = blk >> 6;   // 0..7
  const int h = bh & 15, b = bh >> 4;

  const int64_t qrow0 = (int64_t)b * 1024 + qb * 128;
  const int hoff = h * 64;
  const uint16_t* Vtb = Vt + (int64_t)b * 1024 * 2048;

  const float sc = 0.125f * 1.4426950408889634f;  // scale * log2(e)

  // Q B-frags for 2 subtiles: n=ls -> qrow w*32+qq*16+ls; k=lg*8+j -> d
  s16x8 qf[2][2];
#pragma unroll
  for (int qq = 0; qq < 2; qq++)
#pragma unroll
    for (int ks = 0; ks < 2; ks++) {
      s16x8 r = *(const s16x8*)(Q + (qrow0 + w * 32 + qq * 16 + ls) * 1024 + hoff + ks * 32 + lg * 8);
#pragma unroll
      for (int j = 0; j < 8; j++)
        qf[qq][ks][j] = (short)f2bf(bf2f((uint16_t)r[j]) * sc);
    }

  f32x4 oacc[2][4] = {};
  float lsum[2] = {0.f, 0.f};

  // staging: 256 threads, rows 0..31 (+32) x 16B chunks
  const int srow = tid >> 3;      // 0..31
  const int sc8 = (tid & 7) * 8;  // 0..56
  const uint16_t* Kg = KV + ((int64_t)b * 2048 + srow) * 2048 + hoff + sc8;
  const uint16_t* Vg = Vtb + (int64_t)(hoff + srow) * 2048 + sc8;

  s16x8 rk0 = *(const s16x8*)(Kg);
  s16x8 rk1 = *(const s16x8*)(Kg + (int64_t)32 * 2048);
  s16x8 rv0 = *(const s16x8*)(Vg);
  s16x8 rv1 = *(const s16x8*)(Vg + (int64_t)32 * 2048);

  for (int kt = 0; kt < 2048; kt += 64) {
    __syncthreads();
    *(s16x8*)&Ks[srow * KLD + sc8] = rk0;
    *(s16x8*)&Ks[(srow + 32) * KLD + sc8] = rk1;
    *(s16x8*)&Vts[srow * KLD + sc8] = rv0;
    *(s16x8*)&Vts[(srow + 32) * KLD + sc8] = rv1;
    const int ktn = kt + 64;
    if (ktn < 2048) {  // register prefetch, hidden behind MFMAs
      rk0 = *(const s16x8*)(Kg + (int64_t)ktn * 2048);
      rk1 = *(const s16x8*)(Kg + (int64_t)(ktn + 32) * 2048);
      rv0 = *(const s16x8*)(Vg + ktn);
      rv1 = *(const s16x8*)(Vg + ktn + (int64_t)32 * 2048);
    }
    __syncthreads();

    // S^T = K Q^T for both subtiles; each K-frag read feeds 2 MFMAs
    f32x4 st[2][4];
#pragma unroll
    for (int jn = 0; jn < 4; jn++) {
      f32x4 z = {0.f, 0.f, 0.f, 0.f};
      st[0][jn] = z; st[1][jn] = z;
#pragma unroll
      for (int ks = 0; ks < 2; ks++) {
        s16x8 kf = *(const s16x8*)&Ks[(jn * 16 + ls) * KLD + ks * 32 + lg * 8];
        st[0][jn] = __builtin_amdgcn_mfma_f32_16x16x32_bf16(kf, qf[0][ks], st[0][jn], 0, 0, 0);
        st[1][jn] = __builtin_amdgcn_mfma_f32_16x16x32_bf16(kf, qf[1][ks], st[1][jn], 0, 0, 0);
      }
    }

    // P = exp2(S^T), fixed M=0; pack 4 consecutive keys -> one b64 write
#pragma unroll
    for (int qq = 0; qq < 2; qq++)
#pragma unroll
      for (int jn = 0; jn < 4; jn++) {
        const float p0 = exp2f(st[qq][jn][0]);
        const float p1 = exp2f(st[qq][jn][1]);
        const float p2 = exp2f(st[qq][jn][2]);
        const float p3 = exp2f(st[qq][jn][3]);
        lsum[qq] += (p0 + p1) + (p2 + p3);
        uint2 pk; pk.x = pkbf(p0, p1); pk.y = pkbf(p2, p3);
        *(uint2*)&Ps[w * 2 + qq][ls * PLD + jn * 16 + lg * 4] = pk;
      }
    // same-wave DS ordering: writes land before this wave's reads below

    // O += P V ; each V-frag read feeds both subtiles
#pragma unroll
    for (int ks = 0; ks < 2; ks++) {
      s16x8 pf0 = *(const s16x8*)&Ps[w * 2 + 0][ls * PLD + ks * 32 + lg * 8];
      s16x8 pf1 = *(const s16x8*)&Ps[w * 2 + 1][ls * PLD + ks * 32 + lg * 8];
#pragma unroll
      for (int jn = 0; jn < 4; jn++) {
        s16x8 vf = *(const s16x8*)&Vts[(jn * 16 + ls) * KLD + ks * 32 + lg * 8];
        oacc[0][jn] = __builtin_amdgcn_mfma_f32_16x16x32_bf16(pf0, vf, oacc[0][jn], 0, 0, 0);
        oacc[1][jn] = __builtin_amdgcn_mfma_f32_16x16x32_bf16(pf1, vf, oacc[1][jn], 0, 0, 0);
      }
    }
  }

  // reduce lane-local sums across the 4 lg groups; lane (ls,*) -> sum(qrow=ls)
#pragma unroll
  for (int qq = 0; qq < 2; qq++) {
    float red = lsum[qq];
    red += __shfl_xor(red, 16, 64);
    red += __shfl_xor(red, 32, 64);
    // epilogue: oacc C-layout col=ls -> d, row=lg*4+rr -> local qrow
#pragma unroll
    for (int rr = 0; rr < 4; rr++) {
      const float inv = 1.0f / __shfl(red, lg * 4 + rr, 64);
      const int64_t row = qrow0 + w * 32 + qq * 16 + lg * 4 + rr;
#pragma unroll
      for (int jn = 0; jn < 4; jn++)
        O[row * 1024 + hoff + jn * 16 + ls] = f2bf(oacc[qq][jn][rr] * inv);
    }
  }
}

// ---------------- host ----------------
extern "C" void kernel_launch(void* const* d_in, const int* in_sizes, int n_in,
                              void* d_out, int out_size, void* d_ws, size_t ws_size,
                              hipStream_t stream) {
  const void* x_raw   = d_in[0];
  const void* ctx_raw = d_in[1];
  const void* Wq_raw  = d_in[2];
  const void* Wk_raw  = d_in[3];
  const void* Wv_raw  = d_in[4];
  const void* Wo_raw  = d_in[5];
  const void* bo_raw  = d_in[6];
  const void* W1_raw  = d_in[7];
  const void* b1_raw  = d_in[8];
  const void* W2_raw  = d_in[9];
  const void* b2_raw  = d_in[10];

  const int64_t Mi = 1 << 20;
  uint16_t* ws   = (uint16_t*)d_ws;
  uint16_t* WqT  = ws;                  // [0,1M)
  uint16_t* KVWt = ws + 1 * Mi;         // [1M,3M)  [2048][1024] = [WkT;WvT]
  uint16_t* WoT  = ws + 3 * Mi;         // [3M,4M)
  uint16_t* W1T  = ws + 4 * Mi;         // [4M,8M)   [4096][1024]
  uint16_t* W2T  = ws + 8 * Mi;         // [8M,12M)  [1024][4096]
  uint16_t* bob  = ws + 12 * Mi;
  uint16_t* b1b  = ws + 12 * Mi + 1024;
  uint16_t* b2b  = ws + 12 * Mi + 5120;
  uint16_t* xb   = ws + 13 * Mi;        // [13M,17M) dead after Q-proj
  uint16_t* AO   = ws + 13 * Mi;        // alias xb (born in attention)
  uint16_t* ctxb = ws + 17 * Mi;        // [17M,25M) dead after KV-proj
  uint16_t* Vt   = ws + 17 * Mi;        // alias ctxb (born after KV-proj)
  uint16_t* X1   = ws + 17 * Mi;        // alias Vt (born after attention)
  uint16_t* Qb   = ws + 25 * Mi;        // [25M,29M)
  uint16_t* KVb  = ws + 29 * Mi;        // [29M,45M) [8192][2048]; dead after attn
  uint16_t* Hb   = ws + 29 * Mi;        // alias KVb (born at FF1)
  // peak ws: 45M elements = 90 MB

  const dim3 tb(256);
  // one fused prep dispatch: zero d_out + converts + all 6 weight transposes
  prep_all<<<dim3(19459), tb, 0, stream>>>(
      (float*)d_out,
      x_raw, ctx_raw, bo_raw, b1_raw, b2_raw,
      Wq_raw, Wk_raw, Wv_raw, Wo_raw, W1_raw, W2_raw,
      xb, ctxb, bob, b1b, b2b,
      WqT, KVWt, KVWt + Mi, WoT, W1T, W2T);

  // grouped Q-proj + fused KV-proj (1280 blocks)
  gemm_qkv<<<dim3(1280), tb, 0, stream>>>(xb, WqT, Qb, ctxb, KVWt, KVb);

  // fused per-batch V transpose
  vtrans<<<dim3(32, 64, 4), tb, 0, stream>>>(KVb, Vt);

  attn_kernel<<<dim3(512), tb, 0, stream>>>(Qb, KVb, Vt, AO);

  // out-proj + bias + residual(x, fp32 direct)
  gemm_single<EPI_BIAS_RES, 1, 0, 0><<<dim3(32, 8), tb, 0, stream>>>(
      AO, WoT, X1, bob, x_raw, 4096, 1024, 1024);
  // FF1 + bias + exact GELU
  gemm_single<EPI_BIAS_GELU, 0, 0, 0><<<dim3(32, 32), tb, 0, stream>>>(
      X1, W1T, Hb, b1b, nullptr, 4096, 4096, 1024);
  // FF2 + bias + residual(X1), split-K2, fp32 atomics into zeroed d_out
  gemm_single<EPI_BIAS_RES, 0, 1, 1><<<dim3(32, 8, 2), tb, 0, stream>>>(
      Hb, W2T, d_out, b2b, X1, 4096, 1024, 4096);
}

// Round 10
// 416.945 us; speedup vs baseline: 1.0862x; 1.0862x over previous
//
#include <hip/hip_runtime.h>
#include <hip/hip_bf16.h>
#include <cmath>
#include <cstdint>

typedef short s16x8 __attribute__((ext_vector_type(8)));
typedef unsigned short u16x8 __attribute__((ext_vector_type(8)));
typedef unsigned short u16x4 __attribute__((ext_vector_type(4)));
typedef float f32x4 __attribute__((ext_vector_type(4)));

__device__ __forceinline__ float bf2f(uint16_t u) {
  union { uint32_t i; float f; } c; c.i = ((uint32_t)u) << 16; return c.f;
}
__device__ __forceinline__ uint16_t f2bf(float f) {
  union { float f; uint32_t i; } c; c.f = f;
  return (uint16_t)((c.i + 0x7FFFu + ((c.i >> 16) & 1u)) >> 16);
}
// packed f32x2 -> bf16x2 (RNE), low word = a
__device__ __forceinline__ uint32_t pkbf(float a, float b) {
  union { __hip_bfloat162 h; uint32_t u; } c;
  c.h = __float22bfloat162_rn(float2{a, b});
  return c.u;
}

// async global->LDS, 16B/lane; lane i lands at (uniform base) + 16*i
__device__ __forceinline__ void gload16(const void* g, void* l) {
  __builtin_amdgcn_global_load_lds(
      (const __attribute__((address_space(1))) void*)g,
      (__attribute__((address_space(3))) void*)l, 16, 0, 0);
}

// ---- dtype sniff: bf16 data -> even 16-bit words have sane exponents ----
__device__ __forceinline__ bool sniff_is_bf16(const uint16_t* u16, int64_t n,
                                              int tid, int* s_cnt) {
  int cnt = 0;
#pragma unroll
  for (int j = 0; j < 4; j++) {
    int64_t idx = (((int64_t)(tid * 4 + j)) * 2) % n;
    idx &= ~(int64_t)1;
    uint32_t e = (u16[idx] >> 7) & 0xFF;
    cnt += (e >= 96 && e <= 144) ? 1 : 0;
  }
  if (tid == 0) *s_cnt = 0;
  __syncthreads();
  atomicAdd(s_cnt, cnt);
  __syncthreads();
  return (*s_cnt) * 10 > 1024 * 6;
}

// ------ ONE fused prep dispatch (all paths vectorized, 16B/lane) -----------
// [0,1024): zero d_out(16MB, f32x4 x4); [1024,2048): cvt x; [2048,4096): cvt ctx;
// 4096..4098: biases; [4099,5123): 64x64 transposes Wq/Wk/Wv/Wo;
// [5123,6147): W1; [6147,7171): W2.
__global__ __launch_bounds__(256) void prep_all(
    float* dout,
    const void* xr, const void* cr, const void* bor, const void* b1r, const void* b2r,
    const void* Wq, const void* Wk, const void* Wv, const void* Wo,
    const void* W1, const void* W2,
    uint16_t* xo, uint16_t* co, uint16_t* boo, uint16_t* b1o, uint16_t* b2o,
    uint16_t* WqT, uint16_t* WkT, uint16_t* WvT, uint16_t* WoT,
    uint16_t* W1T, uint16_t* W2T) {
  __shared__ int s_cnt;
  __shared__ uint16_t tile[64][65];
  const int id = blockIdx.x;
  const int tid = threadIdx.x;

  if (id < 1024) {  // zero d_out: 4 x f32x4 per thread
    float* p = dout + ((int64_t)id * 256 + tid) * 4;
#pragma unroll
    for (int i = 0; i < 4; i++)
      *(f32x4*)(p + (int64_t)i * 262144) = (f32x4){0.f, 0.f, 0.f, 0.f};
    return;
  }
  if (id < 4099) {  // vectorized converts
    const void* src; uint16_t* dst; int64_t tot; int64_t base; int nv;
    if (id < 2048)      { src = xr; dst = xo; tot = 4194304; base = (int64_t)(id - 1024) * 4096; nv = 4; }
    else if (id < 4096) { src = cr; dst = co; tot = 8388608; base = (int64_t)(id - 2048) * 4096; nv = 4; }
    else if (id == 4096){ src = bor; dst = boo; tot = 1024; base = 0; nv = 1; }
    else if (id == 4097){ src = b1r; dst = b1o; tot = 4096; base = 0; nv = 4; }
    else                { src = b2r; dst = b2o; tot = 1024; base = 0; nv = 1; }
    const bool is16 = sniff_is_bf16((const uint16_t*)src, tot, tid, &s_cnt);
    if (is16) {  // already bf16: copy 8B/lane
      const uint64_t* s = (const uint64_t*)((const uint16_t*)src + base);
      uint64_t* d = (uint64_t*)(dst + base);
      for (int i = 0; i < nv; i++) d[i * 256 + tid] = s[i * 256 + tid];
    } else {  // fp32 -> bf16: float4 load, packed cvt, 8B store
      const f32x4* s = (const f32x4*)((const float*)src + base);
      uint2* d = (uint2*)(dst + base);
      for (int i = 0; i < nv; i++) {
        f32x4 v = s[i * 256 + tid];
        uint2 o; o.x = pkbf(v[0], v[1]); o.y = pkbf(v[2], v[3]);
        d[i * 256 + tid] = o;
      }
    }
    return;
  }
  // 64x64 fp32->bf16 transposes: in[R][C] -> out[C][R]
  const int t0 = id - 4099;
  const void* src; uint16_t* dst; int R, C, bx, by;
  if (t0 < 1024) {  // Wq/Wk/Wv/Wo, 256 tiles each (16x16)
    const int wsel = t0 >> 8, t = t0 & 255;
    const void* srcs[4] = {Wq, Wk, Wv, Wo};
    uint16_t* dsts[4] = {WqT, WkT, WvT, WoT};
    src = srcs[wsel]; dst = dsts[wsel]; R = 1024; C = 1024; bx = t & 15; by = t >> 4;
  } else if (t0 < 2048) { int t = t0 - 1024; src = W1; dst = W1T; R = 1024; C = 4096; bx = t & 63; by = t >> 6; }
  else                  { int t = t0 - 2048; src = W2; dst = W2T; R = 4096; C = 1024; bx = t & 15; by = t >> 4; }
  const uint16_t* u16 = (const uint16_t*)src;
  const float* f32 = (const float*)src;
  const bool is16 = sniff_is_bf16(u16, (int64_t)R * C, tid, &s_cnt);
  const int c0 = bx * 64, r0 = by * 64;
  // load 16B/lane + transpose-scatter into LDS (b16, <=2-way banks)
  if (is16) {
    const int c8 = (tid & 7) * 8, r = tid >> 3;  // 32 rows/pass, 2 passes
#pragma unroll
    for (int ri = 0; ri < 2; ri++) {
      const int row = r + ri * 32;
      u16x8 v = *(const u16x8*)(u16 + (int64_t)(r0 + row) * C + c0 + c8);
#pragma unroll
      for (int j = 0; j < 8; j++) tile[c8 + j][row] = v[j];
    }
  } else {
    const int c4 = (tid & 15) * 4, r = tid >> 4;  // 16 rows/pass, 4 passes
#pragma unroll
    for (int ri = 0; ri < 4; ri++) {
      const int row = r + ri * 16;
      f32x4 v = *(const f32x4*)(f32 + (int64_t)(r0 + row) * C + c0 + c4);
#pragma unroll
      for (int j = 0; j < 4; j++) tile[c4 + j][row] = f2bf(v[j]);
    }
  }
  __syncthreads();
  // write 16B/lane contiguous
  const int rr8 = (tid & 7) * 8, cc = tid >> 3;
#pragma unroll
  for (int ci = 0; ci < 2; ci++) {
    const int col = cc + ci * 32;
    *(u16x8*)(dst + (int64_t)(c0 + col) * R + r0 + rr8) = *(const u16x8*)&tile[col][rr8];
  }
}

// ---- per-batch V transpose (vectorized): KVb[b*2048+k][1024+c] -> Vt[b][c][k]
// grid (16, 32, 4): 64x64 bf16 tiles, 16B reads + 16B writes.
__global__ __launch_bounds__(256) void vtrans(
    const uint16_t* __restrict__ KVb, uint16_t* __restrict__ Vt) {
  __shared__ uint16_t tile[64][65];
  const int z = blockIdx.z;
  const uint16_t* in = KVb + (int64_t)z * 2048 * 2048 + 1024;  // [2048 k][1024 c] stride 2048
  uint16_t* out = Vt + (int64_t)z * 1024 * 2048;               // [1024 c][2048 k]
  const int tid = threadIdx.x;
  const int c0 = blockIdx.x * 64, k0 = blockIdx.y * 64;
  const int c8 = (tid & 7) * 8, r = tid >> 3;
#pragma unroll
  for (int ri = 0; ri < 2; ri++) {
    const int krow = r + ri * 32;
    u16x8 v = *(const u16x8*)(in + (int64_t)(k0 + krow) * 2048 + c0 + c8);
#pragma unroll
    for (int j = 0; j < 8; j++) tile[c8 + j][krow] = v[j];
  }
  __syncthreads();
  const int k8 = (tid & 7) * 8, cc = tid >> 3;
#pragma unroll
  for (int ci = 0; ci < 2; ci++) {
    const int col = cc + ci * 32;
    *(u16x8*)(out + (int64_t)(c0 + col) * 2048 + k0 + k8) = *(const u16x8*)&tile[col][k8];
  }
}

// ---------------- GEMM v4: BK=64, global_load_lds, XOR chunk swizzle ------
#define BM 128
#define BN 128
#define BK 64

enum { EPI_NONE = 0, EPI_BIAS_RES = 1, EPI_BIAS_GELU = 2 };

template <int EPI, int RESF32, int OUTF32, int SPLITK>
__device__ __forceinline__ void gemm_body(
    const uint16_t* __restrict__ A, const uint16_t* __restrict__ Bt,
    void* __restrict__ Cv, const uint16_t* __restrict__ bias,
    const void* __restrict__ resid, int M, int N, int K_total,
    int m0, int n0, int zslice, uint16_t* As, uint16_t* Bs) {
  const int tid = threadIdx.x;
  const int w = tid >> 6, l = tid & 63;
  const int wu = __builtin_amdgcn_readfirstlane(w);
  const int wm = (w >> 1) * 64, wn = (w & 1) * 64;
  const int ls = l & 15, lg = l >> 4;
  const int K = SPLITK ? (K_total >> 1) : K_total;
  const int kof = SPLITK ? zslice * K : 0;

  const int sr = 8 * w + (l >> 3);
  const int koff = (((l & 7) ^ ((l >> 3) & 7)) * 8);
  const uint16_t* Ag = A + (int64_t)(m0 + sr) * K_total + kof + koff;
  const uint16_t* Bg = Bt + (int64_t)(n0 + sr) * K_total + kof + koff;
  const int64_t rstep = (int64_t)32 * K_total;

  uint16_t* lA = As + wu * 512;
  uint16_t* lB = Bs + wu * 512;

  f32x4 acc[4][4] = {};

  for (int kb = 0; kb < K; kb += BK) {
    __syncthreads();
#pragma unroll
    for (int r = 0; r < 4; r++) {
      gload16(Ag + r * rstep + kb, lA + r * 2048);
      gload16(Bg + r * rstep + kb, lB + r * 2048);
    }
    __syncthreads();
#pragma unroll
    for (int kk = 0; kk < 2; kk++) {
      s16x8 af[4], bfr[4];
#pragma unroll
      for (int i = 0; i < 4; i++) {
        const int row = wm + i * 16 + ls;
        af[i] = *(const s16x8*)&As[row * 64 + (((kk * 4 + lg) ^ (ls & 7)) * 8)];
      }
#pragma unroll
      for (int j = 0; j < 4; j++) {
        const int row = wn + j * 16 + ls;
        bfr[j] = *(const s16x8*)&Bs[row * 64 + (((kk * 4 + lg) ^ (ls & 7)) * 8)];
      }
#pragma unroll
      for (int i = 0; i < 4; i++)
#pragma unroll
        for (int j = 0; j < 4; j++)
          acc[i][j] = __builtin_amdgcn_mfma_f32_16x16x32_bf16(af[i], bfr[j], acc[i][j], 0, 0, 0);
    }
  }

#pragma unroll
  for (int i = 0; i < 4; i++) {
#pragma unroll
    for (int rr = 0; rr < 4; rr++) {
      const int64_t row = m0 + wm + i * 16 + lg * 4 + rr;
#pragma unroll
      for (int j = 0; j < 4; j++) {
        const int col = n0 + wn + j * 16 + ls;
        float v = acc[i][j][rr];
        if (EPI == EPI_BIAS_RES) {
          if (!SPLITK || zslice == 0) {
            const float rv = RESF32 ? ((const float*)resid)[row * N + col]
                                    : bf2f(((const uint16_t*)resid)[row * N + col]);
            v += bf2f(bias[col]) + rv;
          }
        } else if (EPI == EPI_BIAS_GELU) {
          v += bf2f(bias[col]);
          v = 0.5f * v * (1.0f + erff(v * 0.70710678118654752f));  // exact GELU
        }
        if (SPLITK)
          atomicAdd((float*)Cv + row * N + col, v);
        else if (OUTF32)
          ((float*)Cv)[row * N + col] = v;
        else
          ((uint16_t*)Cv)[row * N + col] = f2bf(v);
      }
    }
  }
}

template <int EPI, int RESF32, int OUTF32, int SPLITK>
__global__ __launch_bounds__(256, 3) void gemm_single(
    const uint16_t* __restrict__ A, const uint16_t* __restrict__ Bt,
    void* __restrict__ Cv, const uint16_t* __restrict__ bias,
    const void* __restrict__ resid, int M, int N, int K_total) {
  __shared__ alignas(16) uint16_t As[BM * BK];
  __shared__ alignas(16) uint16_t Bs[BN * BK];
  gemm_body<EPI, RESF32, OUTF32, SPLITK>(A, Bt, Cv, bias, resid, M, N, K_total,
                                         blockIdx.x * BM, blockIdx.y * BN,
                                         (int)blockIdx.z, As, Bs);
}

// grouped Q-proj + KV-proj: blocks [0,256) Q, [256,1280) KV. K=1024 both.
__global__ __launch_bounds__(256, 3) void gemm_qkv(
    const uint16_t* __restrict__ xA, const uint16_t* __restrict__ WqT,
    uint16_t* __restrict__ Qb,
    const uint16_t* __restrict__ ctxA, const uint16_t* __restrict__ KVWt,
    uint16_t* __restrict__ KVb) {
  __shared__ alignas(16) uint16_t As[BM * BK];
  __shared__ alignas(16) uint16_t Bs[BN * BK];
  const int id = blockIdx.x;
  if (id < 256) {
    gemm_body<EPI_NONE, 0, 0, 0>(xA, WqT, Qb, nullptr, nullptr, 4096, 1024, 1024,
                                 (id & 31) * BM, (id >> 5) * BN, 0, As, Bs);
  } else {
    const int t = id - 256;
    gemm_body<EPI_NONE, 0, 0, 0>(ctxA, KVWt, KVb, nullptr, nullptr, 8192, 2048, 1024,
                                 (t & 63) * BM, (t >> 6) * BN, 0, As, Bs);
  }
}

// ---------------- flash cross-attention v5 (unchanged from R9) ------------
#define KLD 72
#define PLD 72

__global__ __launch_bounds__(256, 2) void attn_kernel(
    const uint16_t* __restrict__ Q,   // [B*1024][1024]
    const uint16_t* __restrict__ KV,  // [B*2048][2048]; cols 0..1023 = K
    const uint16_t* __restrict__ Vt,  // [B][1024 (h*64+d)][2048 (key)]
    uint16_t* __restrict__ O) {       // [B*1024][1024]
  __shared__ alignas(16) uint16_t Ks[64 * KLD];
  __shared__ alignas(16) uint16_t Vts[64 * KLD];
  __shared__ alignas(16) uint16_t Ps[8][16 * PLD];  // [w*2+qq]

  const int tid = threadIdx.x;
  const int w = tid >> 6, l = tid & 63;
  const int ls = l & 15, lg = l >> 4;

  const int blk = blockIdx.x;
  const int bh = blk & 63;   // XCD = bh%8 for all 8 q-blocks of this (b,h)
  const int qb = blk >> 6;   // 0..7
  const int h = bh & 15, b = bh >> 4;

  const int64_t qrow0 = (int64_t)b * 1024 + qb * 128;
  const int hoff = h * 64;
  const uint16_t* Vtb = Vt + (int64_t)b * 1024 * 2048;

  const float sc = 0.125f * 1.4426950408889634f;  // scale * log2(e)

  s16x8 qf[2][2];
#pragma unroll
  for (int qq = 0; qq < 2; qq++)
#pragma unroll
    for (int ks = 0; ks < 2; ks++) {
      s16x8 r = *(const s16x8*)(Q + (qrow0 + w * 32 + qq * 16 + ls) * 1024 + hoff + ks * 32 + lg * 8);
#pragma unroll
      for (int j = 0; j < 8; j++)
        qf[qq][ks][j] = (short)f2bf(bf2f((uint16_t)r[j]) * sc);
    }

  f32x4 oacc[2][4] = {};
  float lsum[2] = {0.f, 0.f};

  const int srow = tid >> 3;      // 0..31
  const int sc8 = (tid & 7) * 8;  // 0..56
  const uint16_t* Kg = KV + ((int64_t)b * 2048 + srow) * 2048 + hoff + sc8;
  const uint16_t* Vg = Vtb + (int64_t)(hoff + srow) * 2048 + sc8;

  s16x8 rk0 = *(const s16x8*)(Kg);
  s16x8 rk1 = *(const s16x8*)(Kg + (int64_t)32 * 2048);
  s16x8 rv0 = *(const s16x8*)(Vg);
  s16x8 rv1 = *(const s16x8*)(Vg + (int64_t)32 * 2048);

  for (int kt = 0; kt < 2048; kt += 64) {
    __syncthreads();
    *(s16x8*)&Ks[srow * KLD + sc8] = rk0;
    *(s16x8*)&Ks[(srow + 32) * KLD + sc8] = rk1;
    *(s16x8*)&Vts[srow * KLD + sc8] = rv0;
    *(s16x8*)&Vts[(srow + 32) * KLD + sc8] = rv1;
    const int ktn = kt + 64;
    if (ktn < 2048) {
      rk0 = *(const s16x8*)(Kg + (int64_t)ktn * 2048);
      rk1 = *(const s16x8*)(Kg + (int64_t)(ktn + 32) * 2048);
      rv0 = *(const s16x8*)(Vg + ktn);
      rv1 = *(const s16x8*)(Vg + ktn + (int64_t)32 * 2048);
    }
    __syncthreads();

    f32x4 st[2][4];
#pragma unroll
    for (int jn = 0; jn < 4; jn++) {
      f32x4 z = {0.f, 0.f, 0.f, 0.f};
      st[0][jn] = z; st[1][jn] = z;
#pragma unroll
      for (int ks = 0; ks < 2; ks++) {
        s16x8 kf = *(const s16x8*)&Ks[(jn * 16 + ls) * KLD + ks * 32 + lg * 8];
        st[0][jn] = __builtin_amdgcn_mfma_f32_16x16x32_bf16(kf, qf[0][ks], st[0][jn], 0, 0, 0);
        st[1][jn] = __builtin_amdgcn_mfma_f32_16x16x32_bf16(kf, qf[1][ks], st[1][jn], 0, 0, 0);
      }
    }

#pragma unroll
    for (int qq = 0; qq < 2; qq++)
#pragma unroll
      for (int jn = 0; jn < 4; jn++) {
        const float p0 = exp2f(st[qq][jn][0]);
        const float p1 = exp2f(st[qq][jn][1]);
        const float p2 = exp2f(st[qq][jn][2]);
        const float p3 = exp2f(st[qq][jn][3]);
        lsum[qq] += (p0 + p1) + (p2 + p3);
        uint2 pk; pk.x = pkbf(p0, p1); pk.y = pkbf(p2, p3);
        *(uint2*)&Ps[w * 2 + qq][ls * PLD + jn * 16 + lg * 4] = pk;
      }

#pragma unroll
    for (int ks = 0; ks < 2; ks++) {
      s16x8 pf0 = *(const s16x8*)&Ps[w * 2 + 0][ls * PLD + ks * 32 + lg * 8];
      s16x8 pf1 = *(const s16x8*)&Ps[w * 2 + 1][ls * PLD + ks * 32 + lg * 8];
#pragma unroll
      for (int jn = 0; jn < 4; jn++) {
        s16x8 vf = *(const s16x8*)&Vts[(jn * 16 + ls) * KLD + ks * 32 + lg * 8];
        oacc[0][jn] = __builtin_amdgcn_mfma_f32_16x16x32_bf16(pf0, vf, oacc[0][jn], 0, 0, 0);
        oacc[1][jn] = __builtin_amdgcn_mfma_f32_16x16x32_bf16(pf1, vf, oacc[1][jn], 0, 0, 0);
      }
    }
  }

#pragma unroll
  for (int qq = 0; qq < 2; qq++) {
    float red = lsum[qq];
    red += __shfl_xor(red, 16, 64);
    red += __shfl_xor(red, 32, 64);
#pragma unroll
    for (int rr = 0; rr < 4; rr++) {
      const float inv = 1.0f / __shfl(red, lg * 4 + rr, 64);
      const int64_t row = qrow0 + w * 32 + qq * 16 + lg * 4 + rr;
#pragma unroll
      for (int jn = 0; jn < 4; jn++)
        O[row * 1024 + hoff + jn * 16 + ls] = f2bf(oacc[qq][jn][rr] * inv);
    }
  }
}

// ---------------- host ----------------
extern "C" void kernel_launch(void* const* d_in, const int* in_sizes, int n_in,
                              void* d_out, int out_size, void* d_ws, size_t ws_size,
                              hipStream_t stream) {
  const void* x_raw   = d_in[0];
  const void* ctx_raw = d_in[1];
  const void* Wq_raw  = d_in[2];
  const void* Wk_raw  = d_in[3];
  const void* Wv_raw  = d_in[4];
  const void* Wo_raw  = d_in[5];
  const void* bo_raw  = d_in[6];
  const void* W1_raw  = d_in[7];
  const void* b1_raw  = d_in[8];
  const void* W2_raw  = d_in[9];
  const void* b2_raw  = d_in[10];

  const int64_t Mi = 1 << 20;
  uint16_t* ws   = (uint16_t*)d_ws;
  uint16_t* WqT  = ws;                  // [0,1M)
  uint16_t* KVWt = ws + 1 * Mi;         // [1M,3M)  [2048][1024] = [WkT;WvT]
  uint16_t* WoT  = ws + 3 * Mi;         // [3M,4M)
  uint16_t* W1T  = ws + 4 * Mi;         // [4M,8M)   [4096][1024]
  uint16_t* W2T  = ws + 8 * Mi;         // [8M,12M)  [1024][4096]
  uint16_t* bob  = ws + 12 * Mi;
  uint16_t* b1b  = ws + 12 * Mi + 1024;
  uint16_t* b2b  = ws + 12 * Mi + 5120;
  uint16_t* xb   = ws + 13 * Mi;        // [13M,17M) dead after Q-proj
  uint16_t* AO   = ws + 13 * Mi;        // alias xb (born in attention)
  uint16_t* ctxb = ws + 17 * Mi;        // [17M,25M) dead after KV-proj
  uint16_t* Vt   = ws + 17 * Mi;        // alias ctxb (born after KV-proj)
  uint16_t* X1   = ws + 17 * Mi;        // alias Vt (born after attention)
  uint16_t* Qb   = ws + 25 * Mi;        // [25M,29M)
  uint16_t* KVb  = ws + 29 * Mi;        // [29M,45M) [8192][2048]; dead after attn
  uint16_t* Hb   = ws + 29 * Mi;        // alias KVb (born at FF1)
  // peak ws: 45M elements = 90 MB

  const dim3 tb(256);
  // one fused prep dispatch (vectorized): zero + converts + 6 transposes
  prep_all<<<dim3(7171), tb, 0, stream>>>(
      (float*)d_out,
      x_raw, ctx_raw, bo_raw, b1_raw, b2_raw,
      Wq_raw, Wk_raw, Wv_raw, Wo_raw, W1_raw, W2_raw,
      xb, ctxb, bob, b1b, b2b,
      WqT, KVWt, KVWt + Mi, WoT, W1T, W2T);

  // grouped Q-proj + fused KV-proj (1280 blocks)
  gemm_qkv<<<dim3(1280), tb, 0, stream>>>(xb, WqT, Qb, ctxb, KVWt, KVb);

  // per-batch V transpose (vectorized 64x64 tiles)
  vtrans<<<dim3(16, 32, 4), tb, 0, stream>>>(KVb, Vt);

  attn_kernel<<<dim3(512), tb, 0, stream>>>(Qb, KVb, Vt, AO);

  // out-proj + bias + residual(x, fp32 direct)
  gemm_single<EPI_BIAS_RES, 1, 0, 0><<<dim3(32, 8), tb, 0, stream>>>(
      AO, WoT, X1, bob, x_raw, 4096, 1024, 1024);
  // FF1 + bias + exact GELU
  gemm_single<EPI_BIAS_GELU, 0, 0, 0><<<dim3(32, 32), tb, 0, stream>>>(
      X1, W1T, Hb, b1b, nullptr, 4096, 4096, 1024);
  // FF2 + bias + residual(X1), split-K2, fp32 atomics into zeroed d_out
  gemm_single<EPI_BIAS_RES, 0, 1, 1><<<dim3(32, 8, 2), tb, 0, stream>>>(
      Hb, W2T, d_out, b2b, X1, 4096, 1024, 4096);
}